// Round 14
// baseline (4695.918 us; speedup 1.0000x reference)
//
#include <hip/hip_runtime.h>
#include <math.h>

#define LL 16

// ws layout (u32 units)
#define OFF_A8  0        // 32768 : A-phase W_hcat i8 (16 uint4/thread) - R11 layout
#define OFF_BF  32768    // 49152 : B-phase W_hh i8 MFMA fragments (24 uint4/thread)
#define OFF_SRB 81920    // 768 f32 : per-row scale of W_hh
#define OFF_SRA 82688    // 256 f32 : per-row scale of W_hcat
#define OFF_GA  82944    // 768 f32 : W_ih[:,0]-W_ih[:,1]
#define OFF_GBI 83712    // 768 f32 : W_ih[:,1]+b_ih

typedef int i32x4 __attribute__((ext_vector_type(4)));

__device__ __forceinline__ int sdot4(unsigned a, unsigned b, int acc) {
#if __has_builtin(__builtin_amdgcn_sdot4)
    return __builtin_amdgcn_sdot4((int)a, (int)b, acc, false);
#else
    int s = acc;
    #pragma unroll
    for (int r = 0; r < 4; ++r)
        s += (int)(signed char)(a >> (8 * r)) * (int)(signed char)(b >> (8 * r));
    return s;
#endif
}
__device__ __forceinline__ float fsig(float v) { return 1.f / (1.f + __expf(-v)); }
__device__ __forceinline__ float ftanh_(float v) {
    v = fminf(fmaxf(v, -15.f), 15.f);
    float e = __expf(-2.f * v);
    return (1.f - e) / (1.f + e);
}
__device__ __forceinline__ int clampi8(int q) {
    return q > 127 ? 127 : (q < -127 ? -127 : q);
}
template <int CTRL>
__device__ __forceinline__ float dppf(float x) {
    return __builtin_bit_cast(float, __builtin_amdgcn_update_dpp(
        0, __builtin_bit_cast(int, x), CTRL, 0xF, 0xF, true));
}
__device__ __forceinline__ float max16(float x) {
    x = fmaxf(x, dppf<0xB1>(x));
    x = fmaxf(x, dppf<0x4E>(x));
    x = fmaxf(x, dppf<0x124>(x));
    x = fmaxf(x, dppf<0x128>(x));
    return x;
}
__device__ __forceinline__ float sum16(float x) {
    x += dppf<0xB1>(x);
    x += dppf<0x4E>(x);
    x += dppf<0x124>(x);
    x += dppf<0x128>(x);
    return x;
}

// 6 MFMAs (one hint-frag x 6 weight-frags) + hazard nops. Outputs early-clobber.
#define MFMA6(d0,d1,d2,d3,d4,d5, a_, b0,b1,b2,b3,b4,b5, cz)            \
    asm volatile(                                                       \
        "v_mfma_i32_16x16x64_i8 %0, %6, %7, %13\n\t"                  \
        "v_mfma_i32_16x16x64_i8 %1, %6, %8, %13\n\t"                  \
        "v_mfma_i32_16x16x64_i8 %2, %6, %9, %13\n\t"                  \
        "v_mfma_i32_16x16x64_i8 %3, %6, %10, %13\n\t"                 \
        "v_mfma_i32_16x16x64_i8 %4, %6, %11, %13\n\t"                 \
        "v_mfma_i32_16x16x64_i8 %5, %6, %12, %13\n\t"                 \
        "s_nop 7\n\t"                                                  \
        "s_nop 7"                                                      \
        : "=&v"(d0), "=&v"(d1), "=&v"(d2), "=&v"(d3), "=&v"(d4), "=&v"(d5) \
        : "v"(a_), "a"(b0), "a"(b1), "a"(b2), "a"(b3), "a"(b4), "a"(b5), "v"(cz))

// per-row max-abs scales: rows 0..767 = W_hh, 768..1023 = W_hcat
__global__ __launch_bounds__(64)
void gru2d_prep1(const float* __restrict__ W_hh, const float* __restrict__ W_hcat,
                 float* __restrict__ ws) {
    int row = blockIdx.x, lane = threadIdx.x;
    float s = 0.f;
    if (row < 768) {
        for (int k = lane; k < 256; k += 64) s = fmaxf(s, fabsf(W_hh[row * 256 + k]));
    } else {
        int r = row - 768;
        for (int k = lane; k < 512; k += 64) s = fmaxf(s, fabsf(W_hcat[r * 512 + k]));
    }
    #pragma unroll
    for (int o = 32; o > 0; o >>= 1) s = fmaxf(s, __shfl_down(s, o));
    if (lane == 0) {
        float sc = (s > 0.f) ? s * (1.f / 127.f) : 1.f;
        if (row < 768) ws[OFF_SRB + row] = sc;
        else           ws[OFF_SRA + (row - 768)] = sc;
    }
}

// A8: unchanged R11 (2 rows x k-quarter of [Wh_l|Wh_u]).
// BF: MFMA B-fragments of W_hh^T. Wave v owns N-tiles {g*16+2v+p}, frag fb=g*2+p,
//     K-tiles kt=0..3 (K=64 of hint). Lane l: col=l&15 (gate-row within tile),
//     k = kt*64 + (l>>4)*16 + j*4 + byte.  Stored [(fb*4+kt)*512 + t]*4 + j.
__global__ __launch_bounds__(256)
void gru2d_prep2(const float* __restrict__ W_ih, const float* __restrict__ W_hh,
                 const float* __restrict__ b_ih, const float* __restrict__ W_hcat,
                 float* __restrict__ ws) {
    unsigned* __restrict__ wsu = (unsigned*)ws;
    int m = blockIdx.x * 256 + threadIdx.x;
    if (m < 32768) {
        int g = m >> 11, t = (m >> 2) & 511, r = m & 3;
        int jj = g * 4 + r;
        int v = t >> 6, l = t & 63, lr = l & 31, sub = l >> 5, q2 = lr >> 4;
        int row = (v << 5) + (lr & 15) + ((jj >> 5) << 4);
        int j = jj & 31;
        int qk = (sub << 1) | q2;
        float inv = 1.f / ws[OFF_SRA + row];
        int base = row * 512 + (qk << 7) + 4 * j;
        unsigned pk = 0;
        #pragma unroll
        for (int bb = 0; bb < 4; ++bb) {
            int qv = clampi8(__float2int_rn(W_hcat[base + bb] * inv));
            pk |= ((unsigned)(qv & 255)) << (8 * bb);
        }
        wsu[OFF_A8 + m] = pk;
    } else if (m < 81920) {
        int mm = m - 32768;
        int j = mm & 3, t = (mm >> 2) & 511, fi = mm >> 11;   // fi in [0,24)
        int fb = fi >> 2, kt = fi & 3;
        int g3 = fb >> 1, p = fb & 1;
        int v = t >> 6, l = t & 63;
        int n = g3 * 256 + (2 * v + p) * 16 + (l & 15);
        float inv = 1.f / ws[OFF_SRB + n];
        int kb = kt * 64 + ((l >> 4) << 4) + 4 * j;
        unsigned pk = 0;
        #pragma unroll
        for (int bb = 0; bb < 4; ++bb) {
            int qv = clampi8(__float2int_rn(W_hh[n * 256 + kb + bb] * inv));
            pk |= ((unsigned)(qv & 255)) << (8 * bb);
        }
        wsu[OFF_BF + mm] = pk;
    } else if (m < 82688) {
        int e = m - 81920;
        float w0 = W_ih[2 * e], w1 = W_ih[2 * e + 1];
        ws[OFF_GA + e] = w0 - w1;
        ws[OFF_GBI + e] = w1 + b_ih[e];
    }
}

// 512 threads, 1 block/CU, 2 batches/block. Phase A: R11 sdot4. Phase B: MFMA
// (weights in AGPR - relieves the 128-arch cap). 4 barriers/step.
__global__ __launch_bounds__(512)
void gru2d_main(const float* __restrict__ x, const float* __restrict__ b_hh,
                const float* __restrict__ W_fc, const float* __restrict__ b_fc,
                const float* __restrict__ W_xcat, const float* __restrict__ ws,
                float* __restrict__ out) {
    __shared__ __attribute__((aligned(16))) unsigned h8[2][64];
    __shared__ __attribute__((aligned(16))) unsigned hp8[2][LL][64];
    __shared__ __attribute__((aligned(16))) float hs8[2][8];
    __shared__ __attribute__((aligned(16))) float hps8[2][LL][8];
    __shared__ __attribute__((aligned(16))) unsigned hint8q[16][64];  // batch-padded i8 hint
    __shared__ __attribute__((aligned(16))) float dqs[4][2];          // hint 64-chunk scales
    __shared__ float wvA[8][2];                                       // per-wave hint maxes
    __shared__ float ghLDS[3][2][256];                                // gh interchange
    __shared__ float fcp[2][2][8];
    __shared__ float sx[2][256];

    const int tid = threadIdx.x;
    const int v = tid >> 6, l = tid & 63;
    const int lr = l & 31, sub = l >> 5;
    const int q2 = lr >> 4;
    const int w = (v << 5) + lr;
    const int rA0 = (v << 5) + (lr & 15);
    const int b0 = blockIdx.x * 2;
    const unsigned* __restrict__ wsu = (const unsigned*)ws;

    // ---- A weights (arch VGPR) ----
    unsigned wA8[64];
    #pragma unroll
    for (int g = 0; g < 16; ++g) {
        uint4 q = ((const uint4*)(wsu + OFF_A8))[g * 512 + tid];
        wA8[4*g] = q.x; wA8[4*g+1] = q.y; wA8[4*g+2] = q.z; wA8[4*g+3] = q.w;
    }
    // ---- B weight fragments (AGPR-homed) ----
    i32x4 bf[24];
    #pragma unroll
    for (int j = 0; j < 24; ++j)
        bf[j] = __builtin_bit_cast(i32x4, ((const uint4*)(wsu + OFF_BF))[j * 512 + tid]);
    i32x4 zacc = {0, 0, 0, 0};

    const float asc0 = ws[OFF_SRA + rA0];
    const float asc1 = ws[OFF_SRA + rA0 + 16];
    float bA[3], bBi[3], bbh[3], bsr[3];
    #pragma unroll
    for (int g = 0; g < 3; ++g) {
        bA[g]  = ws[OFF_GA + (g << 8) + w];
        bBi[g] = ws[OFF_GBI + (g << 8) + w];
        bbh[g] = b_hh[(g << 8) + w];
        bsr[g] = ws[OFF_SRB + (g << 8) + w];
    }
    const float wfc0 = W_fc[w], wfc1 = W_fc[256 + w];
    sx[tid >> 8][tid & 255] = x[(b0 + (tid >> 8)) * 256 + (tid & 255)];
    {
        unsigned* hp = (unsigned*)hp8;
        #pragma unroll
        for (int g = 0; g < 4; ++g) hp[g * 512 + tid] = 0u;
        if (tid < 256) ((float*)hps8)[tid] = 0.f;
        ((unsigned*)hint8q)[tid] = 0u;             // zero batch-pad (full array)
        ((unsigned*)hint8q)[tid + 512] = 0u;
    }
    const float xc0 = W_xcat[0], xc1 = W_xcat[1];
    const float bf0c = b_fc[0], bf1c = b_fc[1];
    float lp_acc = 0.f;
    __syncthreads();

    for (int i = 0; i < LL; ++i) {
        const int odd = i & 1;
        const int dir = odd ? -1 : 1;
        const int c0g = odd ? (LL - 1) : 0;
        for (int t = 0; t < LL; ++t) {
            const int col = c0g + dir * t;
            const int sidx = (i << 4) + t;

            // anti-remat pins: A weights (arch), B frags (AGPR), zero acc
            #pragma unroll
            for (int g = 0; g < 16; ++g)
                asm volatile("" : "+v"(wA8[4*g]), "+v"(wA8[4*g+1]), "+v"(wA8[4*g+2]), "+v"(wA8[4*g+3]));
            #pragma unroll
            for (int j = 0; j < 24; ++j)
                asm volatile("" : "+a"(bf[j]));
            asm volatile("" : "+v"(zacc));

            // ---- prev-step FC finalize ----
            if ((tid == 0 || tid == 256) && sidx > 0) {
                const int b = tid >> 8;
                int ps = sidx - 1, pi2 = ps >> 4, pt2 = ps & 15;
                int pcol = (pi2 & 1) ? (15 - pt2) : pt2;
                float l0 = bf0c, l1 = bf1c;
                #pragma unroll
                for (int vv = 0; vv < 8; ++vv) { l0 += fcp[b][0][vv]; l1 += fcp[b][1][vv]; }
                float mx = fmaxf(l0, l1);
                float lse = mx + logf(__expf(l0 - mx) + __expf(l1 - mx));
                float xcur = sx[b][(pi2 << 4) + pcol];
                float mm = (1.f + xcur) * 0.5f;
                float lp = (l0 - lse) * mm + (l1 - lse) * (1.f - mm);
                if (pi2 == 0 && pcol == 0) lp = 1.f - mm;
                lp_acc += lp;
            }

            // ---- Phase A (R11): rows rA0,rA1 x both batches over k-quarter ----
            float hi_sel;
            float m_;
            {
                float f00 = 0.f, f01 = 0.f, f10 = 0.f, f11 = 0.f;
                if (!(sub == 0 && t == 0)) {
                    const uint4* H0;
                    const uint4* H1;
                    const float4* S0;
                    const float4* S1;
                    if (sub == 0) {
                        H0 = ((const uint4*)h8[0]) + (q2 << 3);
                        H1 = ((const uint4*)h8[1]) + (q2 << 3);
                        S0 = ((const float4*)hs8[0]) + q2;
                        S1 = ((const float4*)hs8[1]) + q2;
                    } else {
                        H0 = ((const uint4*)hp8[0][col]) + (q2 << 3);
                        H1 = ((const uint4*)hp8[1][col]) + (q2 << 3);
                        S0 = ((const float4*)hps8[0][col]) + q2;
                        S1 = ((const float4*)hps8[1][col]) + q2;
                    }
                    const float4 sc0 = *S0, sc1 = *S1;
                    #pragma unroll
                    for (int c = 0; c < 4; ++c) {
                        uint4 ua0 = H0[2*c], ub0 = H0[2*c+1];
                        uint4 ua1 = H1[2*c], ub1 = H1[2*c+1];
                        const int e = c << 3;
                        int a00 = 0, a01 = 0, a10 = 0, a11 = 0;
                        a00 = sdot4(wA8[e],   ua0.x, a00); a00 = sdot4(wA8[e+1], ua0.y, a00);
                        a00 = sdot4(wA8[e+2], ua0.z, a00); a00 = sdot4(wA8[e+3], ua0.w, a00);
                        a00 = sdot4(wA8[e+4], ub0.x, a00); a00 = sdot4(wA8[e+5], ub0.y, a00);
                        a00 = sdot4(wA8[e+6], ub0.z, a00); a00 = sdot4(wA8[e+7], ub0.w, a00);
                        a10 = sdot4(wA8[32+e],   ua0.x, a10); a10 = sdot4(wA8[32+e+1], ua0.y, a10);
                        a10 = sdot4(wA8[32+e+2], ua0.z, a10); a10 = sdot4(wA8[32+e+3], ua0.w, a10);
                        a10 = sdot4(wA8[32+e+4], ub0.x, a10); a10 = sdot4(wA8[32+e+5], ub0.y, a10);
                        a10 = sdot4(wA8[32+e+6], ub0.z, a10); a10 = sdot4(wA8[32+e+7], ub0.w, a10);
                        a01 = sdot4(wA8[e],   ua1.x, a01); a01 = sdot4(wA8[e+1], ua1.y, a01);
                        a01 = sdot4(wA8[e+2], ua1.z, a01); a01 = sdot4(wA8[e+3], ua1.w, a01);
                        a01 = sdot4(wA8[e+4], ub1.x, a01); a01 = sdot4(wA8[e+5], ub1.y, a01);
                        a01 = sdot4(wA8[e+6], ub1.z, a01); a01 = sdot4(wA8[e+7], ub1.w, a01);
                        a11 = sdot4(wA8[32+e],   ua1.x, a11); a11 = sdot4(wA8[32+e+1], ua1.y, a11);
                        a11 = sdot4(wA8[32+e+2], ua1.z, a11); a11 = sdot4(wA8[32+e+3], ua1.w, a11);
                        a11 = sdot4(wA8[32+e+4], ub1.x, a11); a11 = sdot4(wA8[32+e+5], ub1.y, a11);
                        a11 = sdot4(wA8[32+e+6], ub1.z, a11); a11 = sdot4(wA8[32+e+7], ub1.w, a11);
                        const float s0c = ((const float*)&sc0)[c];
                        const float s1c = ((const float*)&sc1)[c];
                        f00 += (float)a00 * s0c; f01 += (float)a01 * s1c;
                        f10 += (float)a10 * s0c; f11 += (float)a11 * s1c;
                    }
                    f00 *= asc0; f01 *= asc0;
                    f10 *= asc1; f11 *= asc1;
                }
                f00 += __shfl_xor(f00, 16); f00 += __shfl_xor(f00, 32);
                f01 += __shfl_xor(f01, 16); f01 += __shfl_xor(f01, 32);
                f10 += __shfl_xor(f10, 16); f10 += __shfl_xor(f10, 32);
                f11 += __shfl_xor(f11, 16); f11 += __shfl_xor(f11, 32);
                hi_sel = q2 ? (sub ? f11 : f10) : (sub ? f01 : f00);
                m_ = fmaxf(fabsf(sub ? f01 : f00), fabsf(sub ? f11 : f10));
                m_ = max16(m_);
                if (lr == 0) wvA[v][sub] = m_;   // per-wave (32-row) max, batch=sub
            }
            __syncthreads();  // B1a: wave maxes ready

            // ---- combine to 64-chunk scale, quantize hint ----
            {
                const int ch = v >> 1;
                float cs = fmaxf(wvA[ch * 2][sub], wvA[ch * 2 + 1][sub]);
                float qsc = 127.f / fmaxf(cs, 1e-20f);
                int q = clampi8(__float2int_rn(hi_sel * qsc));
                ((unsigned char*)hint8q)[(sub << 8) + w] = (unsigned char)(q & 255);
                if (lr == 0 && !(v & 1)) dqs[ch][sub] = cs * (1.f / 127.f);
            }
            __syncthreads();  // B1b: hint8q/dqs ready

            // ---- Phase B: MFMA gh^T = hint^T @ W_hh^T ----
            {
                float4 dqv0 = ((const float4*)dqs)[0];  // kt0{b0,b1}, kt1{b0,b1}
                float4 dqv1 = ((const float4*)dqs)[1];  // kt2{b0,b1}, kt3{b0,b1}
                const uint4* hqA = (const uint4*)hint8q;
                const int abase = ((l & 15) << 4) + (l >> 4);
                float gh00=0.f,gh01=0.f,gh10=0.f,gh11=0.f,gh20=0.f,gh21=0.f;
                float gh30=0.f,gh31=0.f,gh40=0.f,gh41=0.f,gh50=0.f,gh51=0.f;
                #pragma unroll
                for (int kt = 0; kt < 4; ++kt) {
                    i32x4 af = __builtin_bit_cast(i32x4, hqA[abase + (kt << 2)]);
                    i32x4 d0, d1, d2, d3, d4, d5;
                    MFMA6(d0, d1, d2, d3, d4, d5, af,
                          bf[0*4+kt], bf[1*4+kt], bf[2*4+kt],
                          bf[3*4+kt], bf[4*4+kt], bf[5*4+kt], zacc);
                    const float dk0 = (kt == 0) ? dqv0.x : (kt == 1) ? dqv0.z
                                     : (kt == 2) ? dqv1.x : dqv1.z;
                    const float dk1 = (kt == 0) ? dqv0.y : (kt == 1) ? dqv0.w
                                     : (kt == 2) ? dqv1.y : dqv1.w;
                    gh00 += (float)d0[0] * dk0; gh01 += (float)d0[1] * dk1;
                    gh10 += (float)d1[0] * dk0; gh11 += (float)d1[1] * dk1;
                    gh20 += (float)d2[0] * dk0; gh21 += (float)d2[1] * dk1;
                    gh30 += (float)d3[0] * dk0; gh31 += (float)d3[1] * dk1;
                    gh40 += (float)d4[0] * dk0; gh41 += (float)d4[1] * dk1;
                    gh50 += (float)d5[0] * dk0; gh51 += (float)d5[1] * dk1;
                }
                // valid data in lanes l<16 (D rows 0,1 = batches). fb = g3*2+p.
                if (l < 16) {
                    const int r0 = (2 * v) * 16 + l, r1 = (2 * v + 1) * 16 + l;
                    ghLDS[0][0][r0] = gh00; ghLDS[0][1][r0] = gh01;
                    ghLDS[0][0][r1] = gh10; ghLDS[0][1][r1] = gh11;
                    ghLDS[1][0][r0] = gh20; ghLDS[1][1][r0] = gh21;
                    ghLDS[1][0][r1] = gh30; ghLDS[1][1][r1] = gh31;
                    ghLDS[2][0][r0] = gh40; ghLDS[2][1][r0] = gh41;
                    ghLDS[2][0][r1] = gh50; ghLDS[2][1][r1] = gh51;
                }
            }
            __syncthreads();  // B2: gh ready

            // ---- gates + h update + FC (R11 roles: thread (w, batch=sub)) ----
            {
                float GR = ghLDS[0][sub][w] * bsr[0];
                float GZ = ghLDS[1][sub][w] * bsr[1];
                float GN = ghLDS[2][sub][w] * bsr[2];
                float xl = (t == 0) ? 0.f : sx[sub][(i << 4) + col - dir];
                float xu = (i == 0) ? 0.f : sx[sub][((i - 1) << 4) + col];
                float pu = (xl * xc0 + xu * xc1 + 1.f) * 0.5f;
                float rr_ = fsig(bA[0] * pu + bBi[0] + GR + bbh[0]);
                float zz = fsig(bA[1] * pu + bBi[1] + GZ + bbh[1]);
                float nn = ftanh_(bA[2] * pu + bBi[2] + rr_ * (GN + bbh[2]));
                float hn = (1.f - zz) * nn + zz * hi_sel;

                float am = max16(fabsf(hn));
                am = fmaxf(am, __shfl_xor(am, 16));
                float qs = 127.f / fmaxf(am, 1e-20f);
                int q = clampi8(__float2int_rn(hn * qs));
                ((unsigned char*)h8)[(sub << 8) + w] = (unsigned char)(q & 255);
                ((unsigned char*)hp8)[(sub << 12) + (col << 8) + w] = (unsigned char)(q & 255);
                if (lr == 0) {
                    float hsc = am * (1.f / 127.f);
                    hs8[sub][v] = hsc;
                    hps8[sub][col][v] = hsc;
                }
                float s0 = hn * wfc0, s1 = hn * wfc1;
                s0 = sum16(s0); s0 += __shfl_xor(s0, 16);
                s1 = sum16(s1); s1 += __shfl_xor(s1, 16);
                if (lr == 0) { fcp[sub][0][v] = s0; fcp[sub][1][v] = s1; }
            }
            __syncthreads();  // B3: h8/scales/fcp ready
        }
    }

    // ---- final step's FC finalize + output ----
    if (tid == 0 || tid == 256) {
        const int b = tid >> 8;
        float l0 = bf0c, l1 = bf1c;
        #pragma unroll
        for (int vv = 0; vv < 8; ++vv) { l0 += fcp[b][0][vv]; l1 += fcp[b][1][vv]; }
        float mx = fmaxf(l0, l1);
        float lse = mx + logf(__expf(l0 - mx) + __expf(l1 - mx));
        float xcur = sx[b][15 * 16 + 0];
        float mm = (1.f + xcur) * 0.5f;
        lp_acc += (l0 - lse) * mm + (l1 - lse) * (1.f - mm);
        out[b0 + b] = lp_acc;
    }
}

extern "C" void kernel_launch(void* const* d_in, const int* in_sizes, int n_in,
                              void* d_out, int out_size, void* d_ws, size_t ws_size,
                              hipStream_t stream) {
    const float* x      = (const float*)d_in[0];
    const float* W_ih   = (const float*)d_in[1];
    const float* W_hh   = (const float*)d_in[2];
    const float* b_ih   = (const float*)d_in[3];
    const float* b_hh   = (const float*)d_in[4];
    const float* W_fc   = (const float*)d_in[5];
    const float* b_fc   = (const float*)d_in[6];
    const float* W_hcat = (const float*)d_in[7];
    const float* W_xcat = (const float*)d_in[8];
    float* out = (float*)d_out;
    float* ws  = (float*)d_ws;

    gru2d_prep1<<<1024, 64, 0, stream>>>(W_hh, W_hcat, ws);
    gru2d_prep2<<<323, 256, 0, stream>>>(W_ih, W_hh, b_ih, W_hcat, ws);
    gru2d_main<<<256, 512, 0, stream>>>(x, b_hh, W_fc, b_fc, W_xcat, ws, out);
}

// Round 15
// 783.641 us; speedup vs baseline: 5.9924x; 5.9924x over previous
//
#include <hip/hip_runtime.h>
#include <math.h>

#define LL 16
#define WD 256
#define G3 768

// ws layout (u32 units)
#define OFF_A8  0        // 32768 u32 : W_hcat i8 (16 uint4/thread; 2 rows x k-quarter)
#define OFF_B8  32768    // 49152 u32 : W_hh i8 (24 uint4/thread)
#define OFF_SRB 81920    // 768 f32 : per-row scale of W_hh
#define OFF_SRA 82688    // 256 f32 : per-row scale of W_hcat
#define OFF_GA  82944    // 768 f32 : W_ih[:,0]-W_ih[:,1]
#define OFF_GBI 83712    // 768 f32 : W_ih[:,1]+b_ih

__device__ __forceinline__ int sdot4(unsigned a, unsigned b, int acc) {
#if __has_builtin(__builtin_amdgcn_sdot4)
    return __builtin_amdgcn_sdot4((int)a, (int)b, acc, false);
#else
    int s = acc;
    #pragma unroll
    for (int r = 0; r < 4; ++r)
        s += (int)(signed char)(a >> (8 * r)) * (int)(signed char)(b >> (8 * r));
    return s;
#endif
}
__device__ __forceinline__ float fsig(float v) { return 1.f / (1.f + __expf(-v)); }
__device__ __forceinline__ float ftanh_(float v) {
    v = fminf(fmaxf(v, -15.f), 15.f);
    float e = __expf(-2.f * v);
    return (1.f - e) / (1.f + e);
}
__device__ __forceinline__ int clampi8(int q) {
    return q > 127 ? 127 : (q < -127 ? -127 : q);
}

// DPP-based intra-16-lane reductions (VALU pipe, not DS).
template <int CTRL>
__device__ __forceinline__ float dppf(float x) {
    return __builtin_bit_cast(float, __builtin_amdgcn_update_dpp(
        0, __builtin_bit_cast(int, x), CTRL, 0xF, 0xF, true));
}
__device__ __forceinline__ float max16(float x) {
    x = fmaxf(x, dppf<0xB1>(x));
    x = fmaxf(x, dppf<0x4E>(x));
    x = fmaxf(x, dppf<0x124>(x));
    x = fmaxf(x, dppf<0x128>(x));
    return x;
}
__device__ __forceinline__ float sum16(float x) {
    x += dppf<0xB1>(x);
    x += dppf<0x4E>(x);
    x += dppf<0x124>(x);
    x += dppf<0x128>(x);
    return x;
}

// per-row max-abs scales: rows 0..767 = W_hh (256-wide), 768..1023 = W_hcat (512-wide)
__global__ __launch_bounds__(64)
void gru2d_prep1(const float* __restrict__ W_hh, const float* __restrict__ W_hcat,
                 float* __restrict__ ws) {
    int row = blockIdx.x, lane = threadIdx.x;
    float s = 0.f;
    if (row < 768) {
        for (int k = lane; k < 256; k += 64) s = fmaxf(s, fabsf(W_hh[row * 256 + k]));
    } else {
        int r = row - 768;
        for (int k = lane; k < 512; k += 64) s = fmaxf(s, fabsf(W_hcat[r * 512 + k]));
    }
    #pragma unroll
    for (int o = 32; o > 0; o >>= 1) s = fmaxf(s, __shfl_down(s, o));
    if (lane == 0) {
        float sc = (s > 0.f) ? s * (1.f / 127.f) : 1.f;
        if (row < 768) ws[OFF_SRB + row] = sc;
        else           ws[OFF_SRA + (row - 768)] = sc;
    }
}

// Main-thread role (t: v=t>>6, l=t&63, lr=l&31, sub=l>>5, q2=lr>>4):
// A8: rows rA0=v*32+(lr&15), rA1=rA0+16 of [Wh_l|Wh_u] as i8,
//     k-quarter qk=(sub<<1)|q2 -> concat-k [qk*128,+128). u32 jj<32 -> rA0 (j=jj),
//     jj>=32 -> rA1 (j=jj-32); u32 j holds k=qk*128+4j..+3.
// B8: gate rows {w,256+w,512+w} (w=v*32+lr) of W_hh as i8, k in [sub*128,+128).
__global__ __launch_bounds__(256)
void gru2d_prep2(const float* __restrict__ W_ih, const float* __restrict__ W_hh,
                 const float* __restrict__ b_ih, const float* __restrict__ W_hcat,
                 float* __restrict__ ws) {
    unsigned* __restrict__ wsu = (unsigned*)ws;
    int m = blockIdx.x * 256 + threadIdx.x;
    if (m < 32768) {
        int g = m >> 11, t = (m >> 2) & 511, r = m & 3;
        int jj = g * 4 + r;
        int v = t >> 6, l = t & 63, lr = l & 31, sub = l >> 5, q2 = lr >> 4;
        int row = (v << 5) + (lr & 15) + ((jj >> 5) << 4);
        int j = jj & 31;
        int qk = (sub << 1) | q2;
        float inv = 1.f / ws[OFF_SRA + row];
        int base = row * 512 + (qk << 7) + 4 * j;
        unsigned pk = 0;
        #pragma unroll
        for (int bb = 0; bb < 4; ++bb) {
            int qv = clampi8(__float2int_rn(W_hcat[base + bb] * inv));
            pk |= ((unsigned)(qv & 255)) << (8 * bb);
        }
        wsu[OFF_A8 + m] = pk;
    } else if (m < 81920) {
        int mm = m - 32768;
        int g4 = mm >> 11, t = (mm >> 2) & 511, rr = mm & 3;
        int ql = g4 * 4 + rr;
        int gate = ql >> 5, q = ql & 31;
        int v = t >> 6, l = t & 63;
        int w = v * 32 + (l & 31), kh = l >> 5;
        int row = gate * 256 + w;
        float inv = 1.f / ws[OFF_SRB + row];
        int kb = row * 256 + kh * 128 + 4 * q;
        unsigned pk = 0;
        #pragma unroll
        for (int bb = 0; bb < 4; ++bb) {
            int qv = clampi8(__float2int_rn(W_hh[kb + bb] * inv));
            pk |= ((unsigned)(qv & 255)) << (8 * bb);
        }
        wsu[OFF_B8 + mm] = pk;
    } else if (m < 82688) {
        int e = m - 81920;
        float w0 = W_ih[2 * e], w1 = W_ih[2 * e + 1];
        ws[OFF_GA + e] = w0 - w1;
        ws[OFF_GBI + e] = w1 + b_ih[e];
    }
}

// 512 threads, 1 block/CU, 2 batches/block. 2 barriers/step. Proven best (R13):
// i8 weights persistent in registers (per-step anti-remat pins), i8 h state,
// intra-wave k-split with shfl_xor cross-k reduce, DPP quant/FC reductions.
__global__ __launch_bounds__(512)
void gru2d_main(const float* __restrict__ x, const float* __restrict__ b_hh,
                const float* __restrict__ W_fc, const float* __restrict__ b_fc,
                const float* __restrict__ W_xcat, const float* __restrict__ ws,
                float* __restrict__ out) {
    __shared__ __attribute__((aligned(16))) unsigned h8[2][64];       // i8 h_left
    __shared__ __attribute__((aligned(16))) unsigned hp8[2][LL][64];  // i8 prev-row h
    __shared__ __attribute__((aligned(16))) float hs8[2][8];          // h chunk scales
    __shared__ __attribute__((aligned(16))) float hps8[2][LL][8];
    __shared__ __attribute__((aligned(16))) unsigned hint8q[2][64];   // i8 hint
    __shared__ __attribute__((aligned(16))) float dqs[2][8];          // hint chunk scales
    __shared__ float fcp[2][2][8];
    __shared__ float sx[2][256];

    const int tid = threadIdx.x;
    const int v = tid >> 6, l = tid & 63;
    const int lr = l & 31, sub = l >> 5;
    const int q2 = lr >> 4;
    const int w = (v << 5) + lr;            // gates / B rows / FC row
    const int rA0 = (v << 5) + (lr & 15);   // A rows: rA0, rA0+16
    const int b0 = blockIdx.x * 2;
    const unsigned* __restrict__ wsu = (const unsigned*)ws;

    // ---- persistent i8 weights -> registers (coalesced uint4) ----
    unsigned wA8[64], wB8[96];
    #pragma unroll
    for (int g = 0; g < 16; ++g) {
        uint4 q = ((const uint4*)(wsu + OFF_A8))[g * 512 + tid];
        wA8[4*g] = q.x; wA8[4*g+1] = q.y; wA8[4*g+2] = q.z; wA8[4*g+3] = q.w;
    }
    #pragma unroll
    for (int g = 0; g < 24; ++g) {
        uint4 q = ((const uint4*)(wsu + OFF_B8))[g * 512 + tid];
        wB8[4*g] = q.x; wB8[4*g+1] = q.y; wB8[4*g+2] = q.z; wB8[4*g+3] = q.w;
    }

    const float asc0 = ws[OFF_SRA + rA0];
    const float asc1 = ws[OFF_SRA + rA0 + 16];
    float bA[3], bBi[3], bbh[3], bsr[3];
    #pragma unroll
    for (int g = 0; g < 3; ++g) {
        bA[g]  = ws[OFF_GA + (g << 8) + w];
        bBi[g] = ws[OFF_GBI + (g << 8) + w];
        bbh[g] = b_hh[(g << 8) + w];
        bsr[g] = ws[OFF_SRB + (g << 8) + w];
    }
    const float wfc0 = W_fc[w], wfc1 = W_fc[256 + w];
    sx[tid >> 8][tid & 255] = x[(b0 + (tid >> 8)) * 256 + (tid & 255)];
    {
        unsigned* hp = (unsigned*)hp8;
        #pragma unroll
        for (int g = 0; g < 4; ++g) hp[g * 512 + tid] = 0u;
        if (tid < 256) ((float*)hps8)[tid] = 0.f;
    }
    const float xc0 = W_xcat[0], xc1 = W_xcat[1];
    const float bf0 = b_fc[0], bf1 = b_fc[1];
    float lp_acc = 0.f;
    __syncthreads();

    for (int i = 0; i < LL; ++i) {
        const int odd = i & 1;
        const int dir = odd ? -1 : 1;
        const int c0g = odd ? (LL - 1) : 0;
        for (int t = 0; t < LL; ++t) {
            const int col = c0g + dir * t;
            const int sidx = (i << 4) + t;

            // per-step pins: USE+DEF each iteration -> spilling would cost a
            // reload per step -> allocator keeps weights resident (proven R5-R13)
            #pragma unroll
            for (int g = 0; g < 16; ++g)
                asm volatile("" : "+v"(wA8[4*g]), "+v"(wA8[4*g+1]), "+v"(wA8[4*g+2]), "+v"(wA8[4*g+3]));
            #pragma unroll
            for (int g = 0; g < 24; ++g)
                asm volatile("" : "+v"(wB8[4*g]), "+v"(wB8[4*g+1]), "+v"(wB8[4*g+2]), "+v"(wB8[4*g+3]));

            // ---- prev-step FC finalize (2 lanes; overlaps other waves' Phase A) ----
            if ((tid == 0 || tid == 256) && sidx > 0) {
                const int b = tid >> 8;
                int ps = sidx - 1, pi2 = ps >> 4, pt2 = ps & 15;
                int pcol = (pi2 & 1) ? (15 - pt2) : pt2;
                float l0 = bf0, l1 = bf1;
                #pragma unroll
                for (int vv = 0; vv < 8; ++vv) { l0 += fcp[b][0][vv]; l1 += fcp[b][1][vv]; }
                float mx = fmaxf(l0, l1);
                float lse = mx + logf(__expf(l0 - mx) + __expf(l1 - mx));
                float xcur = sx[b][(pi2 << 4) + pcol];
                float mm = (1.f + xcur) * 0.5f;
                float lp = (l0 - lse) * mm + (l1 - lse) * (1.f - mm);
                if (pi2 == 0 && pcol == 0) lp = 1.f - mm;
                lp_acc += lp;
            }

            // ---- Phase A: rows rA0,rA1 x both batches over k-quarter qk ----
            float hi_sel;
            {
                float f00 = 0.f, f01 = 0.f, f10 = 0.f, f11 = 0.f; // [row][batch]
                if (!(sub == 0 && t == 0)) {   // qk<2 == h_left side (0 at row start)
                    const uint4* H0;
                    const uint4* H1;
                    const float4* S0;
                    const float4* S1;
                    if (sub == 0) {
                        H0 = ((const uint4*)h8[0]) + (q2 << 3);
                        H1 = ((const uint4*)h8[1]) + (q2 << 3);
                        S0 = ((const float4*)hs8[0]) + q2;
                        S1 = ((const float4*)hs8[1]) + q2;
                    } else {
                        H0 = ((const uint4*)hp8[0][col]) + (q2 << 3);
                        H1 = ((const uint4*)hp8[1][col]) + (q2 << 3);
                        S0 = ((const float4*)hps8[0][col]) + q2;
                        S1 = ((const float4*)hps8[1][col]) + q2;
                    }
                    const float4 sc0 = *S0, sc1 = *S1;
                    #pragma unroll
                    for (int c = 0; c < 4; ++c) {
                        uint4 ua0 = H0[2*c], ub0 = H0[2*c+1];
                        uint4 ua1 = H1[2*c], ub1 = H1[2*c+1];
                        const int e = c << 3;
                        int a00 = 0, a01 = 0, a10 = 0, a11 = 0;
                        a00 = sdot4(wA8[e],   ua0.x, a00); a00 = sdot4(wA8[e+1], ua0.y, a00);
                        a00 = sdot4(wA8[e+2], ua0.z, a00); a00 = sdot4(wA8[e+3], ua0.w, a00);
                        a00 = sdot4(wA8[e+4], ub0.x, a00); a00 = sdot4(wA8[e+5], ub0.y, a00);
                        a00 = sdot4(wA8[e+6], ub0.z, a00); a00 = sdot4(wA8[e+7], ub0.w, a00);
                        a10 = sdot4(wA8[32+e],   ua0.x, a10); a10 = sdot4(wA8[32+e+1], ua0.y, a10);
                        a10 = sdot4(wA8[32+e+2], ua0.z, a10); a10 = sdot4(wA8[32+e+3], ua0.w, a10);
                        a10 = sdot4(wA8[32+e+4], ub0.x, a10); a10 = sdot4(wA8[32+e+5], ub0.y, a10);
                        a10 = sdot4(wA8[32+e+6], ub0.z, a10); a10 = sdot4(wA8[32+e+7], ub0.w, a10);
                        a01 = sdot4(wA8[e],   ua1.x, a01); a01 = sdot4(wA8[e+1], ua1.y, a01);
                        a01 = sdot4(wA8[e+2], ua1.z, a01); a01 = sdot4(wA8[e+3], ua1.w, a01);
                        a01 = sdot4(wA8[e+4], ub1.x, a01); a01 = sdot4(wA8[e+5], ub1.y, a01);
                        a01 = sdot4(wA8[e+6], ub1.z, a01); a01 = sdot4(wA8[e+7], ub1.w, a01);
                        a11 = sdot4(wA8[32+e],   ua1.x, a11); a11 = sdot4(wA8[32+e+1], ua1.y, a11);
                        a11 = sdot4(wA8[32+e+2], ua1.z, a11); a11 = sdot4(wA8[32+e+3], ua1.w, a11);
                        a11 = sdot4(wA8[32+e+4], ub1.x, a11); a11 = sdot4(wA8[32+e+5], ub1.y, a11);
                        a11 = sdot4(wA8[32+e+6], ub1.z, a11); a11 = sdot4(wA8[32+e+7], ub1.w, a11);
                        const float s0c = ((const float*)&sc0)[c];
                        const float s1c = ((const float*)&sc1)[c];
                        f00 += (float)a00 * s0c; f01 += (float)a01 * s1c;
                        f10 += (float)a10 * s0c; f11 += (float)a11 * s1c;
                    }
                    f00 *= asc0; f01 *= asc0;
                    f10 *= asc1; f11 *= asc1;
                }
                // cross-k reduce: xor16 (q2) + xor32 (sub)
                f00 += __shfl_xor(f00, 16); f00 += __shfl_xor(f00, 32);
                f01 += __shfl_xor(f01, 16); f01 += __shfl_xor(f01, 32);
                f10 += __shfl_xor(f10, 16); f10 += __shfl_xor(f10, 32);
                f11 += __shfl_xor(f11, 16); f11 += __shfl_xor(f11, 32);

                // gate-select stays in-register: row w = rA0 + 16*q2, batch = sub
                hi_sel = q2 ? (sub ? f11 : f10) : (sub ? f01 : f00);

                // quant scale: max over 32 rows (chunk v) for batch=sub, DPP-only
                float m_ = fmaxf(fabsf(sub ? f01 : f00), fabsf(sub ? f11 : f10));
                m_ = max16(m_);
                float qsc = 127.f / fmaxf(m_, 1e-20f);
                int q = clampi8(__float2int_rn(hi_sel * qsc));
                ((unsigned char*)hint8q)[(sub << 8) + w] = (unsigned char)(q & 255);
                if (lr == 0) dqs[sub][v] = m_ * (1.f / 127.f);
            }
            __syncthreads();  // B1: hint8q/dqs ready

            // ---- Phase B: gh + gates + h update + FC ----
            {
                const uint4* hq0 = ((const uint4*)hint8q) + (sub << 3);
                const uint4* hq1 = ((const uint4*)hint8q) + 16 + (sub << 3);
                const float4 dq0v = ((const float4*)dqs[0])[sub];
                const float4 dq1v = ((const float4*)dqs[1])[sub];
                float gr0 = 0.f, gz0 = 0.f, gn0 = 0.f, gr1 = 0.f, gz1 = 0.f, gn1 = 0.f;
                #pragma unroll
                for (int c2 = 0; c2 < 4; ++c2) {
                    uint4 u0a = hq0[2*c2], u0b = hq0[2*c2+1];
                    uint4 u1a = hq1[2*c2], u1b = hq1[2*c2+1];
                    const int k = c2 << 3;
                    int r0 = 0, z0 = 0, n0 = 0, r1 = 0, z1 = 0, n1 = 0;
                    r0 = sdot4(wB8[k],      u0a.x, r0); r0 = sdot4(wB8[k+1],    u0a.y, r0);
                    r0 = sdot4(wB8[k+2],    u0a.z, r0); r0 = sdot4(wB8[k+3],    u0a.w, r0);
                    r0 = sdot4(wB8[k+4],    u0b.x, r0); r0 = sdot4(wB8[k+5],    u0b.y, r0);
                    r0 = sdot4(wB8[k+6],    u0b.z, r0); r0 = sdot4(wB8[k+7],    u0b.w, r0);
                    z0 = sdot4(wB8[32+k],   u0a.x, z0); z0 = sdot4(wB8[32+k+1], u0a.y, z0);
                    z0 = sdot4(wB8[32+k+2], u0a.z, z0); z0 = sdot4(wB8[32+k+3], u0a.w, z0);
                    z0 = sdot4(wB8[32+k+4], u0b.x, z0); z0 = sdot4(wB8[32+k+5], u0b.y, z0);
                    z0 = sdot4(wB8[32+k+6], u0b.z, z0); z0 = sdot4(wB8[32+k+7], u0b.w, z0);
                    n0 = sdot4(wB8[64+k],   u0a.x, n0); n0 = sdot4(wB8[64+k+1], u0a.y, n0);
                    n0 = sdot4(wB8[64+k+2], u0a.z, n0); n0 = sdot4(wB8[64+k+3], u0a.w, n0);
                    n0 = sdot4(wB8[64+k+4], u0b.x, n0); n0 = sdot4(wB8[64+k+5], u0b.y, n0);
                    n0 = sdot4(wB8[64+k+6], u0b.z, n0); n0 = sdot4(wB8[64+k+7], u0b.w, n0);
                    r1 = sdot4(wB8[k],      u1a.x, r1); r1 = sdot4(wB8[k+1],    u1a.y, r1);
                    r1 = sdot4(wB8[k+2],    u1a.z, r1); r1 = sdot4(wB8[k+3],    u1a.w, r1);
                    r1 = sdot4(wB8[k+4],    u1b.x, r1); r1 = sdot4(wB8[k+5],    u1b.y, r1);
                    r1 = sdot4(wB8[k+6],    u1b.z, r1); r1 = sdot4(wB8[k+7],    u1b.w, r1);
                    z1 = sdot4(wB8[32+k],   u1a.x, z1); z1 = sdot4(wB8[32+k+1], u1a.y, z1);
                    z1 = sdot4(wB8[32+k+2], u1a.z, z1); z1 = sdot4(wB8[32+k+3], u1a.w, z1);
                    z1 = sdot4(wB8[32+k+4], u1b.x, z1); z1 = sdot4(wB8[32+k+5], u1b.y, z1);
                    z1 = sdot4(wB8[32+k+6], u1b.z, z1); z1 = sdot4(wB8[32+k+7], u1b.w, z1);
                    n1 = sdot4(wB8[64+k],   u1a.x, n1); n1 = sdot4(wB8[64+k+1], u1a.y, n1);
                    n1 = sdot4(wB8[64+k+2], u1a.z, n1); n1 = sdot4(wB8[64+k+3], u1a.w, n1);
                    n1 = sdot4(wB8[64+k+4], u1b.x, n1); n1 = sdot4(wB8[64+k+5], u1b.y, n1);
                    n1 = sdot4(wB8[64+k+6], u1b.z, n1); n1 = sdot4(wB8[64+k+7], u1b.w, n1);
                    const float d0 = ((const float*)&dq0v)[c2];
                    const float d1 = ((const float*)&dq1v)[c2];
                    gr0 += (float)r0 * d0; gz0 += (float)z0 * d0; gn0 += (float)n0 * d0;
                    gr1 += (float)r1 * d1; gz1 += (float)z1 * d1; gn1 += (float)n1 * d1;
                }
                gr0 += __shfl_xor(gr0, 32); gz0 += __shfl_xor(gz0, 32); gn0 += __shfl_xor(gn0, 32);
                gr1 += __shfl_xor(gr1, 32); gz1 += __shfl_xor(gz1, 32); gn1 += __shfl_xor(gn1, 32);

                const int bsel = sub;
                float GR = (bsel ? gr1 : gr0) * bsr[0];
                float GZ = (bsel ? gz1 : gz0) * bsr[1];
                float GN = (bsel ? gn1 : gn0) * bsr[2];
                float xl = (t == 0) ? 0.f : sx[bsel][(i << 4) + col - dir];
                float xu = (i == 0) ? 0.f : sx[bsel][((i - 1) << 4) + col];
                float pu = (xl * xc0 + xu * xc1 + 1.f) * 0.5f;
                float rr_ = fsig(bA[0] * pu + bBi[0] + GR + bbh[0]);
                float zz = fsig(bA[1] * pu + bBi[1] + GZ + bbh[1]);
                float nn = ftanh_(bA[2] * pu + bBi[2] + rr_ * (GN + bbh[2]));
                float hn = (1.f - zz) * nn + zz * hi_sel;

                // h -> i8: max over 32 rows via 4 DPP + 1 shfl(16)
                float am = max16(fabsf(hn));
                am = fmaxf(am, __shfl_xor(am, 16));
                float qs = 127.f / fmaxf(am, 1e-20f);
                int q = clampi8(__float2int_rn(hn * qs));
                ((unsigned char*)h8)[(sub << 8) + w] = (unsigned char)(q & 255);
                ((unsigned char*)hp8)[(sub << 12) + (col << 8) + w] = (unsigned char)(q & 255);
                if (lr == 0) {
                    float hsc = am * (1.f / 127.f);
                    hs8[sub][v] = hsc;
                    hps8[sub][col][v] = hsc;
                }

                // FC partial: sum over 32 lanes via 4 DPP + 1 shfl(16) each
                float s0 = hn * wfc0, s1 = hn * wfc1;
                s0 = sum16(s0); s0 += __shfl_xor(s0, 16);
                s1 = sum16(s1); s1 += __shfl_xor(s1, 16);
                if (lr == 0) { fcp[sub][0][v] = s0; fcp[sub][1][v] = s1; }
            }
            __syncthreads();  // B2: h8/hp8/scales/fcp ready for next step
        }
    }

    // ---- final step's FC finalize + output ----
    if (tid == 0 || tid == 256) {
        const int b = tid >> 8;
        float l0 = bf0, l1 = bf1;
        #pragma unroll
        for (int vv = 0; vv < 8; ++vv) { l0 += fcp[b][0][vv]; l1 += fcp[b][1][vv]; }
        float mx = fmaxf(l0, l1);
        float lse = mx + logf(__expf(l0 - mx) + __expf(l1 - mx));
        float xcur = sx[b][15 * 16 + 0];   // last step: i=15 (odd) -> col 0
        float mm = (1.f + xcur) * 0.5f;
        lp_acc += (l0 - lse) * mm + (l1 - lse) * (1.f - mm);
        out[b0 + b] = lp_acc;
    }
}

extern "C" void kernel_launch(void* const* d_in, const int* in_sizes, int n_in,
                              void* d_out, int out_size, void* d_ws, size_t ws_size,
                              hipStream_t stream) {
    const float* x      = (const float*)d_in[0];
    const float* W_ih   = (const float*)d_in[1];
    const float* W_hh   = (const float*)d_in[2];
    const float* b_ih   = (const float*)d_in[3];
    const float* b_hh   = (const float*)d_in[4];
    const float* W_fc   = (const float*)d_in[5];
    const float* b_fc   = (const float*)d_in[6];
    const float* W_hcat = (const float*)d_in[7];
    const float* W_xcat = (const float*)d_in[8];
    float* out = (float*)d_out;
    float* ws  = (float*)d_ws;

    gru2d_prep1<<<1024, 64, 0, stream>>>(W_hh, W_hcat, ws);
    gru2d_prep2<<<323, 256, 0, stream>>>(W_ih, W_hh, b_ih, W_hcat, ws);
    gru2d_main<<<256, 512, 0, stream>>>(x, b_hh, W_fc, b_fc, W_xcat, ws, out);
}